// Round 2
// baseline (172.619 us; speedup 1.0000x reference)
//
#include <hip/hip_runtime.h>
#include <hip/hip_bf16.h>
#include <stdint.h>

// y[p, j] = sum_i Alpha[p, i] * (X_ref[i] . X_in[j])^expK * [Z_ref[i] == Z[j]]
// Fused: QK^T (MFMA bf16, BK=64, XOR-swizzled LDS) -> square+mask -> PV.
// Deterministic i-split partials + reduce. 3 blocks/CU (49KB LDS).

typedef __attribute__((ext_vector_type(8))) short bf16x8;
typedef __attribute__((ext_vector_type(4))) float f32x4;

#define DFEAT  384
#define NREF   8192
#define NIN    8192
#define NPROPS 64
#define BJ 128
#define BI 128
#define BK 64
#define KSTEPS (DFEAT / BK)        // 6
#define TILES_TOTAL (NREF / BI)    // 64

__device__ __forceinline__ void gload_lds16(const void* g, void* l) {
  __builtin_amdgcn_global_load_lds(
      (const __attribute__((address_space(1))) void*)g,
      (__attribute__((address_space(3))) void*)l,
      16, 0, 0);
}

__device__ __forceinline__ unsigned short bfbits(float f) {
  __hip_bfloat16 h = __float2bfloat16(f);
  return __builtin_bit_cast(unsigned short, h);
}

__device__ __forceinline__ float pwr(float s, int expK) {
  if (expK == 2) return s * s;
  float r = 1.0f;
  for (int e = 0; e < expK; ++e) r *= s;
  return r;
}

__global__ void cvt_f32_bf16(const float* __restrict__ in,
                             __hip_bfloat16* __restrict__ out, int n4) {
  int idx = blockIdx.x * blockDim.x + threadIdx.x;
  if (idx >= n4) return;
  float4 v = *reinterpret_cast<const float4*>(in + (size_t)idx * 4);
  ushort4 o;
  o.x = bfbits(v.x); o.y = bfbits(v.y); o.z = bfbits(v.z); o.w = bfbits(v.w);
  *reinterpret_cast<ushort4*>(out + (size_t)idx * 4) = o;
}

__global__ void reduce_partials(const float* __restrict__ partial,
                                float* __restrict__ out, int nsplit) {
  int idx = blockIdx.x * blockDim.x + threadIdx.x;
  float4 s = make_float4(0.f, 0.f, 0.f, 0.f);
  for (int sp = 0; sp < nsplit; ++sp) {
    float4 v = *reinterpret_cast<const float4*>(
        partial + (size_t)sp * NPROPS * NIN + (size_t)idx * 4);
    s.x += v.x; s.y += v.y; s.z += v.z; s.w += v.w;
  }
  *reinterpret_cast<float4*>(out + (size_t)idx * 4) = s;
}

__global__ __launch_bounds__(256, 3) void fused_poly_kernel(
    const __hip_bfloat16* __restrict__ Xr,   // [NREF][DFEAT] bf16
    const __hip_bfloat16* __restrict__ Xi,   // [NIN][DFEAT] bf16
    const __hip_bfloat16* __restrict__ Ab,   // [NPROPS][NREF] bf16
    const int* __restrict__ Zrq,             // [NREF]
    const int* __restrict__ Zcq,             // [NIN]
    const int* __restrict__ expKp,
    float* __restrict__ partial,             // [nsplit][NPROPS][NIN]
    int nsplit)
{
  const int jblk  = blockIdx.x;
  const int split = blockIdx.y;
  const int j0 = jblk * BJ;

  // uneven tile distribution: base tiles + 1 extra for first `rem` splits
  const int base = TILES_TOTAL / nsplit;
  const int rem  = TILES_TOTAL % nsplit;
  const int ntiles = base + (split < rem ? 1 : 0);
  const int tile_begin = split * base + (split < rem ? split : rem);

  const int tid  = threadIdx.x;
  const int wid  = tid >> 6;      // 4 waves
  const int lane = tid & 63;
  const int l15  = lane & 15;
  const int l4   = lane >> 4;     // 0..3
  const int s7   = l15 & 7;       // row&7 for fragment rows
  const int wi   = wid >> 1;      // wave row over i (2)
  const int wj   = wid & 1;       // wave col over j (2)

  // LDS: lA/lB [128 rows][64 bf16] = 16KB each, row=128B=8 slots of 16B,
  // slot XOR-swizzled by row&7.  lPT: [128 j][64 i] bf16 = 16KB, same swizzle.
  __shared__ alignas(16) __hip_bfloat16 lA[BI * BK];
  __shared__ alignas(16) __hip_bfloat16 lB[BJ * BK];
  __shared__ alignas(16) __hip_bfloat16 lPT[BJ * 64];
  __shared__ int lZr[BI];
  __shared__ int lZc[BJ];

  const int expK = *expKp;
  if (tid < BJ) lZc[tid] = Zcq[j0 + tid];

  // pre-swizzled staging source offsets (rule 21: linear LDS dest,
  // inverse-swizzled global column; 8-lane groups stay within one 128B row)
  const int srow = lane >> 3;                         // row within 8-row chunk
  const int scol = ((lane & 7) ^ srow) * 8;           // swizzled bf16 column

  f32x4 accO[4][2];
  #pragma unroll
  for (int a = 0; a < 4; ++a)
    #pragma unroll
    for (int n = 0; n < 2; ++n)
      accO[a][n] = (f32x4){0.f, 0.f, 0.f, 0.f};

  char* pb = (char*)lPT;

  for (int t = 0; t < ntiles; ++t) {
    const int i0 = (tile_begin + t) * BI;
    if (tid < BI) lZr[tid] = Zrq[i0 + tid];

    f32x4 acc[4][4];
    #pragma unroll
    for (int m = 0; m < 4; ++m)
      #pragma unroll
      for (int n = 0; n < 4; ++n)
        acc[m][n] = (f32x4){0.f, 0.f, 0.f, 0.f};

    // ---- QK^T over K=384, 6 steps of BK=64 ----
    for (int kk = 0; kk < KSTEPS; ++kk) {
      // stage 16KB per array: 16 chunks of 1KB, 4 per wave
      #pragma unroll
      for (int q = 0; q < 4; ++q) {
        const int c = wid * 4 + q;          // chunk 0..15
        const int grow = c * 8 + srow;      // global-local row 0..127
        const size_t gc = (size_t)kk * BK + scol;
        gload_lds16(Xr + (size_t)(i0 + grow) * DFEAT + gc, &lA[c * 512]);
        gload_lds16(Xi + (size_t)(j0 + grow) * DFEAT + gc, &lB[c * 512]);
      }
      __syncthreads();   // drain vmcnt -> tiles visible

      #pragma unroll
      for (int kap = 0; kap < 2; ++kap) {
        bf16x8 aF[4], bF[4];
        #pragma unroll
        for (int m = 0; m < 4; ++m) {
          const int rA = wi * 64 + m * 16 + l15;
          aF[m] = *reinterpret_cast<const bf16x8*>(
              (char*)lA + rA * 128 + (((kap * 4 + l4) ^ s7) << 4));
        }
        #pragma unroll
        for (int n = 0; n < 4; ++n) {
          const int rB = wj * 64 + n * 16 + l15;
          bF[n] = *reinterpret_cast<const bf16x8*>(
              (char*)lB + rB * 128 + (((kap * 4 + l4) ^ s7) << 4));
        }
        #pragma unroll
        for (int m = 0; m < 4; ++m)
          #pragma unroll
          for (int n = 0; n < 4; ++n)
            acc[m][n] = __builtin_amdgcn_mfma_f32_16x16x32_bf16(
                aF[m], bF[n], acc[m][n], 0, 0, 0);
      }
      if (kk < KSTEPS - 1) __syncthreads();   // readers done before next stage
    }

    // ---- P-phase + PV in two i-halves (lPT = [128 j][64 i]) ----
    #pragma unroll
    for (int h = 0; h < 2; ++h) {
      // hoist Alpha fragment loads (L2 latency hides under P-write + barrier)
      bf16x8 aP[2][4];
      #pragma unroll
      for (int ks = 0; ks < 2; ++ks)
        #pragma unroll
        for (int a = 0; a < 4; ++a)
          aP[ks][a] = *reinterpret_cast<const bf16x8*>(
              Ab + (size_t)(a * 16 + l15) * NREF + i0 + h * 64 + ks * 32 + l4 * 8);

      if (wi == h) {
        // write this wave's 64x64 S block as P^T[j][i_local], swizzled
        #pragma unroll
        for (int m = 0; m < 4; ++m) {
          const int irg = wi * 64 + m * 16 + l4 * 4;   // global-local i
          const int z0 = lZr[irg + 0];
          const int z1 = lZr[irg + 1];
          const int z2 = lZr[irg + 2];
          const int z3 = lZr[irg + 3];
          const int sl = m * 2 + (l4 >> 1);            // 16B slot 0..7
          #pragma unroll
          for (int n = 0; n < 4; ++n) {
            const int jl = wj * 64 + n * 16 + l15;
            const int zc = lZc[jl];
            const float p0 = (z0 == zc) ? pwr(acc[m][n][0], expK) : 0.f;
            const float p1 = (z1 == zc) ? pwr(acc[m][n][1], expK) : 0.f;
            const float p2 = (z2 == zc) ? pwr(acc[m][n][2], expK) : 0.f;
            const float p3 = (z3 == zc) ? pwr(acc[m][n][3], expK) : 0.f;
            uint2 v;
            v.x = (uint32_t)bfbits(p0) | ((uint32_t)bfbits(p1) << 16);
            v.y = (uint32_t)bfbits(p2) | ((uint32_t)bfbits(p3) << 16);
            const int off = jl * 128 + ((sl ^ (jl & 7)) << 4) + ((l4 & 1) << 3);
            *reinterpret_cast<uint2*>(pb + off) = v;
          }
        }
      }
      __syncthreads();   // P^T visible (also drains aP vmcnt)

      // PV: O[p][j] += Alpha[p, i-half] * P
      #pragma unroll
      for (int ks = 0; ks < 2; ++ks) {
        #pragma unroll
        for (int n = 0; n < 2; ++n) {
          const int jl = wid * 32 + n * 16 + l15;
          const bf16x8 bP = *reinterpret_cast<const bf16x8*>(
              pb + jl * 128 + (((ks * 4 + l4) ^ s7) << 4));
          #pragma unroll
          for (int a = 0; a < 4; ++a)
            accO[a][n] = __builtin_amdgcn_mfma_f32_16x16x32_bf16(
                aP[ks][a], bP, accO[a][n], 0, 0, 0);
        }
      }
      __syncthreads();   // PV readers done before lPT overwritten
    }
  }

  // ---- epilogue: partial[split][p][j] ----
  float* po = partial + (size_t)split * NPROPS * NIN;
  #pragma unroll
  for (int a = 0; a < 4; ++a)
    #pragma unroll
    for (int n = 0; n < 2; ++n) {
      const int jl = wid * 32 + n * 16 + l15;
      #pragma unroll
      for (int r = 0; r < 4; ++r) {
        const int p = a * 16 + l4 * 4 + r;
        po[(size_t)p * NIN + j0 + jl] = accO[a][n][r];
      }
    }
}

extern "C" void kernel_launch(void* const* d_in, const int* in_sizes, int n_in,
                              void* d_out, int out_size, void* d_ws, size_t ws_size,
                              hipStream_t stream) {
  (void)in_sizes; (void)n_in; (void)out_size;
  const float* Alpha = (const float*)d_in[0];
  const float* X_ref = (const float*)d_in[1];
  const float* desc  = (const float*)d_in[2];
  const int*   Z_ref = (const int*)d_in[3];
  const int*   Z     = (const int*)d_in[4];
  const int*   expK  = (const int*)d_in[5];
  float* out = (float*)d_out;

  char* ws = (char*)d_ws;
  size_t off = 0;
  auto alloc = [&](size_t b) { void* p = ws + off; off = (off + b + 255) & ~255ULL; return p; };

  __hip_bfloat16* Xr_bf = (__hip_bfloat16*)alloc((size_t)NREF * DFEAT * 2);
  __hip_bfloat16* Xi_bf = (__hip_bfloat16*)alloc((size_t)NIN * DFEAT * 2);
  __hip_bfloat16* Ab    = (__hip_bfloat16*)alloc((size_t)NPROPS * NREF * 2);

  // grid = 64 jblocks x nsplit = 768 blocks = exactly 3/CU at nsplit=12
  int nsplit = 12;
  while (nsplit > 1 && off + (size_t)nsplit * NPROPS * NIN * 4 > ws_size) --nsplit;
  float* partial = (float*)alloc((size_t)nsplit * NPROPS * NIN * 4);

  { int n4 = NREF * DFEAT / 4;
    cvt_f32_bf16<<<dim3((n4 + 255) / 256), 256, 0, stream>>>(X_ref, Xr_bf, n4); }
  { int n4 = NIN * DFEAT / 4;
    cvt_f32_bf16<<<dim3((n4 + 255) / 256), 256, 0, stream>>>(desc, Xi_bf, n4); }
  { int n4 = NPROPS * NREF / 4;
    cvt_f32_bf16<<<dim3((n4 + 255) / 256), 256, 0, stream>>>(Alpha, Ab, n4); }

  fused_poly_kernel<<<dim3(NIN / BJ, nsplit), 256, 0, stream>>>(
      Xr_bf, Xi_bf, Ab, Z_ref, Z, expK, partial, nsplit);

  reduce_partials<<<dim3(NPROPS * NIN / 4 / 256), 256, 0, stream>>>(partial, out, nsplit);
}

// Round 3
// 154.397 us; speedup vs baseline: 1.1180x; 1.1180x over previous
//
#include <hip/hip_runtime.h>
#include <hip/hip_bf16.h>
#include <stdint.h>

// y[p, j] = sum_i Alpha[p, i] * (X_ref[i] . X_in[j])^expK * [Z_ref[i] == Z[j]]
// Fused: QK^T (MFMA bf16, BK=64, XOR-swizzled LDS, double-buffered pipelined
// staging with counted-drain raw barriers) -> square+mask -> PV.
// nsplit=8 keeps per-XCD L2 working set < 4MB (round-2 lesson).

typedef __attribute__((ext_vector_type(8))) short bf16x8;
typedef __attribute__((ext_vector_type(4))) float f32x4;

#define DFEAT  384
#define NREF   8192
#define NIN    8192
#define NPROPS 64
#define BJ 128
#define BI 128
#define BK 64
#define KSTEPS (DFEAT / BK)        // 6
#define TILES_TOTAL (NREF / BI)    // 64

__device__ __forceinline__ void gload_lds16(const void* g, void* l) {
  __builtin_amdgcn_global_load_lds(
      (const __attribute__((address_space(1))) void*)g,
      (__attribute__((address_space(3))) void*)l,
      16, 0, 0);
}

__device__ __forceinline__ unsigned short bfbits(float f) {
  __hip_bfloat16 h = __float2bfloat16(f);
  return __builtin_bit_cast(unsigned short, h);
}

__device__ __forceinline__ float pwr(float s, int expK) {
  if (expK == 2) return s * s;
  float r = 1.0f;
  for (int e = 0; e < expK; ++e) r *= s;
  return r;
}

__global__ void cvt_f32_bf16(const float* __restrict__ in,
                             __hip_bfloat16* __restrict__ out, int n4) {
  int idx = blockIdx.x * blockDim.x + threadIdx.x;
  if (idx >= n4) return;
  float4 v = *reinterpret_cast<const float4*>(in + (size_t)idx * 4);
  ushort4 o;
  o.x = bfbits(v.x); o.y = bfbits(v.y); o.z = bfbits(v.z); o.w = bfbits(v.w);
  *reinterpret_cast<ushort4*>(out + (size_t)idx * 4) = o;
}

__global__ void reduce_partials(const float* __restrict__ partial,
                                float* __restrict__ out, int nsplit) {
  int idx = blockIdx.x * blockDim.x + threadIdx.x;
  float4 s = make_float4(0.f, 0.f, 0.f, 0.f);
  for (int sp = 0; sp < nsplit; ++sp) {
    float4 v = *reinterpret_cast<const float4*>(
        partial + (size_t)sp * NPROPS * NIN + (size_t)idx * 4);
    s.x += v.x; s.y += v.y; s.z += v.z; s.w += v.w;
  }
  *reinterpret_cast<float4*>(out + (size_t)idx * 4) = s;
}

__global__ __launch_bounds__(256, 2) void fused_poly_kernel(
    const __hip_bfloat16* __restrict__ Xr,   // [NREF][DFEAT] bf16
    const __hip_bfloat16* __restrict__ Xi,   // [NIN][DFEAT] bf16
    const __hip_bfloat16* __restrict__ Ab,   // [NPROPS][NREF] bf16
    const int* __restrict__ Zrq,             // [NREF]
    const int* __restrict__ Zcq,             // [NIN]
    const int* __restrict__ expKp,
    float* __restrict__ partial,             // [nsplit][NPROPS][NIN]
    int nsplit)
{
  const int jblk  = blockIdx.x;
  const int split = blockIdx.y;
  const int j0 = jblk * BJ;
  const int ntiles = TILES_TOTAL / nsplit;     // nsplit is a power of 2
  const int tile_begin = split * ntiles;

  const int tid  = threadIdx.x;
  const int wid  = tid >> 6;      // 4 waves
  const int lane = tid & 63;
  const int l15  = lane & 15;
  const int l4   = lane >> 4;     // 0..3
  const int s7   = l15 & 7;
  const int wi   = wid >> 1;      // wave row over i (2)
  const int wj   = wid & 1;       // wave col over j (2)

  // LDS = 2*16K (lA) + 2*16K (lB) + 16K (lPT) = 80KB exactly -> 2 blocks/CU
  __shared__ alignas(16) __hip_bfloat16 lA[2][BI * BK];
  __shared__ alignas(16) __hip_bfloat16 lB[2][BJ * BK];
  __shared__ alignas(16) __hip_bfloat16 lPT[BJ * 64];

  const int expK = *expKp;

  // zc registers for mask (jl = wj*64 + n*16 + l15), loaded once
  int zc[4];
  #pragma unroll
  for (int n = 0; n < 4; ++n) zc[n] = Zcq[j0 + wj * 64 + n * 16 + l15];

  // pre-swizzled staging source (rule 21: linear LDS dest, inverse-swizzled
  // global column; 8-lane groups stay within one 128B row)
  const int srow = lane >> 3;
  const int scol = ((lane & 7) ^ srow) * 8;

  auto stage = [&](int buf, int i0s, int kks) {
    #pragma unroll
    for (int q = 0; q < 4; ++q) {
      const int c = wid * 4 + q;          // chunk 0..15 (8 rows x 64 cols)
      const int grow = c * 8 + srow;
      const size_t gc = (size_t)kks * BK + scol;
      gload_lds16(Xr + (size_t)(i0s + grow) * DFEAT + gc, &lA[buf][c * 512]);
      gload_lds16(Xi + (size_t)(j0  + grow) * DFEAT + gc, &lB[buf][c * 512]);
    }
  };

  f32x4 accO[4][2];
  #pragma unroll
  for (int a = 0; a < 4; ++a)
    #pragma unroll
    for (int n = 0; n < 2; ++n)
      accO[a][n] = (f32x4){0.f, 0.f, 0.f, 0.f};

  char* pb = (char*)lPT;

  // ---- pipeline prologue ----
  int cur = 0;
  stage(0, tile_begin * BI, 0);
  asm volatile("s_waitcnt vmcnt(0)" ::: "memory");
  __builtin_amdgcn_s_barrier();

  for (int t = 0; t < ntiles; ++t) {
    const int i0 = (tile_begin + t) * BI;

    f32x4 acc[4][4];
    #pragma unroll
    for (int m = 0; m < 4; ++m)
      #pragma unroll
      for (int n = 0; n < 4; ++n)
        acc[m][n] = (f32x4){0.f, 0.f, 0.f, 0.f};

    // ---- QK^T: 6 pipelined K-steps (stage next || compute cur) ----
    for (int kk = 0; kk < KSTEPS; ++kk) {
      if (kk < KSTEPS - 1) {
        stage(cur ^ 1, i0, kk + 1);            // next K-step of this tile
      } else if (t < ntiles - 1) {
        stage(cur ^ 1, i0 + BI, 0);            // first K-step of next tile
      }

      #pragma unroll
      for (int kap = 0; kap < 2; ++kap) {
        bf16x8 aF[4], bF[4];
        #pragma unroll
        for (int m = 0; m < 4; ++m) {
          const int rA = wi * 64 + m * 16 + l15;
          aF[m] = *reinterpret_cast<const bf16x8*>(
              (char*)(&lA[cur][0]) + rA * 128 + (((kap * 4 + l4) ^ s7) << 4));
        }
        #pragma unroll
        for (int n = 0; n < 4; ++n) {
          const int rB = wj * 64 + n * 16 + l15;
          bF[n] = *reinterpret_cast<const bf16x8*>(
              (char*)(&lB[cur][0]) + rB * 128 + (((kap * 4 + l4) ^ s7) << 4));
        }
        #pragma unroll
        for (int m = 0; m < 4; ++m)
          #pragma unroll
          for (int n = 0; n < 4; ++n)
            acc[m][n] = __builtin_amdgcn_mfma_f32_16x16x32_bf16(
                aF[m], bF[n], acc[m][n], 0, 0, 0);
      }
      // drain next-step loads (hidden under the compute above) + readers-done
      asm volatile("s_waitcnt vmcnt(0) lgkmcnt(0)" ::: "memory");
      __builtin_amdgcn_s_barrier();
      cur ^= 1;
    }

    // ---- P-phase + PV in two i-halves (lPT = [128 j][64 i], swizzled) ----
    #pragma unroll
    for (int h = 0; h < 2; ++h) {
      // hoist Alpha fragment loads (latency hides under P-write + barrier)
      bf16x8 aP[2][4];
      #pragma unroll
      for (int ks = 0; ks < 2; ++ks)
        #pragma unroll
        for (int a = 0; a < 4; ++a)
          aP[ks][a] = *reinterpret_cast<const bf16x8*>(
              Ab + (size_t)(a * 16 + l15) * NREF + i0 + h * 64 + ks * 32 + l4 * 8);

      if (wi == h) {
        #pragma unroll
        for (int m = 0; m < 4; ++m) {
          const int irg = wi * 64 + m * 16 + l4 * 4;   // block-local i row
          const int4 zr = *reinterpret_cast<const int4*>(Zrq + i0 + irg);
          const int sl = m * 2 + (l4 >> 1);            // 16B slot 0..7
          #pragma unroll
          for (int n = 0; n < 4; ++n) {
            const int jl = wj * 64 + n * 16 + l15;
            const int zcv = zc[n];
            const float p0 = (zr.x == zcv) ? pwr(acc[m][n][0], expK) : 0.f;
            const float p1 = (zr.y == zcv) ? pwr(acc[m][n][1], expK) : 0.f;
            const float p2 = (zr.z == zcv) ? pwr(acc[m][n][2], expK) : 0.f;
            const float p3 = (zr.w == zcv) ? pwr(acc[m][n][3], expK) : 0.f;
            uint2 v;
            v.x = (uint32_t)bfbits(p0) | ((uint32_t)bfbits(p1) << 16);
            v.y = (uint32_t)bfbits(p2) | ((uint32_t)bfbits(p3) << 16);
            const int off = jl * 128 + ((sl ^ (jl & 7)) << 4) + ((l4 & 1) << 3);
            *reinterpret_cast<uint2*>(pb + off) = v;
          }
        }
      }
      asm volatile("s_waitcnt lgkmcnt(0)" ::: "memory");   // P^T writes landed
      __builtin_amdgcn_s_barrier();

      // PV: O[p][j] += Alpha[p, i-half] * P
      #pragma unroll
      for (int ks = 0; ks < 2; ++ks) {
        #pragma unroll
        for (int n = 0; n < 2; ++n) {
          const int jl = wid * 32 + n * 16 + l15;
          const bf16x8 bP = *reinterpret_cast<const bf16x8*>(
              pb + jl * 128 + (((ks * 4 + l4) ^ s7) << 4));
          #pragma unroll
          for (int a = 0; a < 4; ++a)
            accO[a][n] = __builtin_amdgcn_mfma_f32_16x16x32_bf16(
                aP[ks][a], bP, accO[a][n], 0, 0, 0);
        }
      }
      asm volatile("s_waitcnt lgkmcnt(0)" ::: "memory");   // PV readers done
      __builtin_amdgcn_s_barrier();
    }
  }

  // ---- epilogue: partial[split][p][j] ----
  float* po = partial + (size_t)split * NPROPS * NIN;
  #pragma unroll
  for (int a = 0; a < 4; ++a)
    #pragma unroll
    for (int n = 0; n < 2; ++n) {
      const int jl = wid * 32 + n * 16 + l15;
      #pragma unroll
      for (int r = 0; r < 4; ++r) {
        const int p = a * 16 + l4 * 4 + r;
        po[(size_t)p * NIN + j0 + jl] = accO[a][n][r];
      }
    }
}

extern "C" void kernel_launch(void* const* d_in, const int* in_sizes, int n_in,
                              void* d_out, int out_size, void* d_ws, size_t ws_size,
                              hipStream_t stream) {
  (void)in_sizes; (void)n_in; (void)out_size;
  const float* Alpha = (const float*)d_in[0];
  const float* X_ref = (const float*)d_in[1];
  const float* desc  = (const float*)d_in[2];
  const int*   Z_ref = (const int*)d_in[3];
  const int*   Z     = (const int*)d_in[4];
  const int*   expK  = (const int*)d_in[5];
  float* out = (float*)d_out;

  char* ws = (char*)d_ws;
  size_t off = 0;
  auto alloc = [&](size_t b) { void* p = ws + off; off = (off + b + 255) & ~255ULL; return p; };

  __hip_bfloat16* Xr_bf = (__hip_bfloat16*)alloc((size_t)NREF * DFEAT * 2);
  __hip_bfloat16* Xi_bf = (__hip_bfloat16*)alloc((size_t)NIN * DFEAT * 2);
  __hip_bfloat16* Ab    = (__hip_bfloat16*)alloc((size_t)NPROPS * NREF * 2);

  // nsplit=8: grid 512 = 2/CU; per-XCD L2 working set ~3.3MB < 4MB (locality)
  int nsplit = 8;
  while (nsplit > 1 && off + (size_t)nsplit * NPROPS * NIN * 4 > ws_size) nsplit >>= 1;
  float* partial = (float*)alloc((size_t)nsplit * NPROPS * NIN * 4);

  { int n4 = NREF * DFEAT / 4;
    cvt_f32_bf16<<<dim3((n4 + 255) / 256), 256, 0, stream>>>(X_ref, Xr_bf, n4); }
  { int n4 = NIN * DFEAT / 4;
    cvt_f32_bf16<<<dim3((n4 + 255) / 256), 256, 0, stream>>>(desc, Xi_bf, n4); }
  { int n4 = NPROPS * NREF / 4;
    cvt_f32_bf16<<<dim3((n4 + 255) / 256), 256, 0, stream>>>(Alpha, Ab, n4); }

  fused_poly_kernel<<<dim3(NIN / BJ, nsplit), 256, 0, stream>>>(
      Xr_bf, Xi_bf, Ab, Z_ref, Z, expK, partial, nsplit);

  reduce_partials<<<dim3(NPROPS * NIN / 4 / 256), 256, 0, stream>>>(partial, out, nsplit);
}

// Round 4
// 117.408 us; speedup vs baseline: 1.4702x; 1.3150x over previous
//
#include <hip/hip_runtime.h>
#include <hip/hip_bf16.h>
#include <stdint.h>

// y[p, j] = sum_i Alpha[p, i] * (X_ref[i] . X_in[j])^expK * [Z_ref[i] == Z[j]]
// Fused: QK^T (MFMA bf16, BK=64, XOR-swizzled dbuf LDS) -> square+mask packed
// in-register -> lane-local PV (no LDS, no tail barriers). Per-wave partial O,
// cross-wi reduce once at kernel end. nsplit=8 for per-XCD L2 residency.

typedef __attribute__((ext_vector_type(8))) short bf16x8;
typedef __attribute__((ext_vector_type(4))) float f32x4;
typedef __attribute__((ext_vector_type(4))) unsigned int u32x4;

#define DFEAT  384
#define NREF   8192
#define NIN    8192
#define NPROPS 64
#define BJ 128
#define BI 128
#define BK 64
#define KSTEPS (DFEAT / BK)        // 6
#define TILES_TOTAL (NREF / BI)    // 64

__device__ __forceinline__ void gload_lds16(const void* g, void* l) {
  __builtin_amdgcn_global_load_lds(
      (const __attribute__((address_space(1))) void*)g,
      (__attribute__((address_space(3))) void*)l,
      16, 0, 0);
}

__device__ __forceinline__ unsigned short bfbits(float f) {
  __hip_bfloat16 h = __float2bfloat16(f);
  return __builtin_bit_cast(unsigned short, h);
}

__device__ __forceinline__ float pwr(float s, int expK) {
  if (expK == 2) return s * s;
  float r = 1.0f;
  for (int e = 0; e < expK; ++e) r *= s;
  return r;
}

__global__ void cvt_f32_bf16(const float* __restrict__ in,
                             __hip_bfloat16* __restrict__ out, int n4) {
  int idx = blockIdx.x * blockDim.x + threadIdx.x;
  if (idx >= n4) return;
  float4 v = *reinterpret_cast<const float4*>(in + (size_t)idx * 4);
  ushort4 o;
  o.x = bfbits(v.x); o.y = bfbits(v.y); o.z = bfbits(v.z); o.w = bfbits(v.w);
  *reinterpret_cast<ushort4*>(out + (size_t)idx * 4) = o;
}

// Alpha -> bf16, permuted within each 32-col block so the PV A-fragment is a
// single 16B load: Abp[p][32b + l4*8 + eh*4 + r] = Alpha[p][32b + eh*16 + l4*4 + r]
__global__ void cvt_alpha_perm(const float* __restrict__ in,
                               __hip_bfloat16* __restrict__ out, int total4) {
  int t = blockIdx.x * blockDim.x + threadIdx.x;
  if (t >= total4) return;
  const int per_row = NREF / 4;
  const int p  = t / per_row;
  const int c4 = t % per_row;
  const int b  = c4 >> 3;
  const int g  = c4 & 7;
  const int l4g = g >> 1;
  const int eh  = g & 1;
  float4 v = *reinterpret_cast<const float4*>(
      in + (size_t)p * NREF + b * 32 + eh * 16 + l4g * 4);
  ushort4 o;
  o.x = bfbits(v.x); o.y = bfbits(v.y); o.z = bfbits(v.z); o.w = bfbits(v.w);
  *reinterpret_cast<ushort4*>(
      out + (size_t)p * NREF + b * 32 + l4g * 8 + eh * 4) = o;
}

__global__ void reduce_partials(const float* __restrict__ partial,
                                float* __restrict__ out, int nsplit) {
  int idx = blockIdx.x * blockDim.x + threadIdx.x;
  float4 s = make_float4(0.f, 0.f, 0.f, 0.f);
  for (int sp = 0; sp < nsplit; ++sp) {
    float4 v = *reinterpret_cast<const float4*>(
        partial + (size_t)sp * NPROPS * NIN + (size_t)idx * 4);
    s.x += v.x; s.y += v.y; s.z += v.z; s.w += v.w;
  }
  *reinterpret_cast<float4*>(out + (size_t)idx * 4) = s;
}

__global__ __launch_bounds__(256, 2) void fused_poly_kernel(
    const __hip_bfloat16* __restrict__ Xr,   // [NREF][DFEAT] bf16
    const __hip_bfloat16* __restrict__ Xi,   // [NIN][DFEAT] bf16
    const __hip_bfloat16* __restrict__ Abp,  // [NPROPS][NREF] bf16, permuted
    const int* __restrict__ Zrq,             // [NREF]
    const int* __restrict__ Zcq,             // [NIN]
    const int* __restrict__ expKp,
    float* __restrict__ partial,             // [nsplit][NPROPS][NIN]
    int nsplit)
{
  const int jblk  = blockIdx.x;
  const int split = blockIdx.y;
  const int j0 = jblk * BJ;
  const int ntiles = TILES_TOTAL / nsplit;
  const int tile_begin = split * ntiles;

  const int tid  = threadIdx.x;
  const int wid  = tid >> 6;      // 4 waves
  const int lane = tid & 63;
  const int l15  = lane & 15;
  const int l4   = lane >> 4;     // 0..3
  const int s7   = l15 & 7;
  const int wi   = wid >> 1;      // wave row over i (2)
  const int wj   = wid & 1;       // wave col over j (2)

  // LDS = dbuf lA (32K) + dbuf lB (32K) = 64KB -> 2 blocks/CU
  __shared__ alignas(16) __hip_bfloat16 lA[2][BI * BK];
  __shared__ alignas(16) __hip_bfloat16 lB[2][BJ * BK];

  const int expK = *expKp;

  // zc for mask (this wave's 64 j-cols: jl = wj*64 + n*16 + l15)
  int zc[4];
  #pragma unroll
  for (int n = 0; n < 4; ++n) zc[n] = Zcq[j0 + wj * 64 + n * 16 + l15];

  // pre-swizzled staging source (linear LDS dest, inverse-swizzled global col)
  const int srow = lane >> 3;
  const int scol = ((lane & 7) ^ srow) * 8;

  auto stage = [&](int buf, int i0s, int kks) {
    #pragma unroll
    for (int q = 0; q < 4; ++q) {
      const int c = wid * 4 + q;          // chunk 0..15 (8 rows x 64 cols)
      const int grow = c * 8 + srow;
      const size_t gc = (size_t)kks * BK + scol;
      gload_lds16(Xr + (size_t)(i0s + grow) * DFEAT + gc, &lA[buf][c * 512]);
      gload_lds16(Xi + (size_t)(j0  + grow) * DFEAT + gc, &lB[buf][c * 512]);
    }
  };

  // per-wave partial O over its own (wi,wj) quadrant: p 64 x j 64
  f32x4 accO[4][4];
  #pragma unroll
  for (int a = 0; a < 4; ++a)
    #pragma unroll
    for (int n = 0; n < 4; ++n)
      accO[a][n] = (f32x4){0.f, 0.f, 0.f, 0.f};

  // ---- pipeline prologue ----
  int cur = 0;
  stage(0, tile_begin * BI, 0);
  asm volatile("s_waitcnt vmcnt(0)" ::: "memory");
  __builtin_amdgcn_s_barrier();

  for (int t = 0; t < ntiles; ++t) {
    const int i0 = (tile_begin + t) * BI;

    f32x4 acc[4][4];
    #pragma unroll
    for (int m = 0; m < 4; ++m)
      #pragma unroll
      for (int n = 0; n < 4; ++n)
        acc[m][n] = (f32x4){0.f, 0.f, 0.f, 0.f};

    // ---- QK^T: 6 pipelined K-steps (stage next || compute cur) ----
    for (int kk = 0; kk < KSTEPS; ++kk) {
      if (kk < KSTEPS - 1) {
        stage(cur ^ 1, i0, kk + 1);
      } else if (t < ntiles - 1) {
        stage(cur ^ 1, i0 + BI, 0);
      }

      __builtin_amdgcn_s_setprio(1);
      #pragma unroll
      for (int kap = 0; kap < 2; ++kap) {
        bf16x8 aF[4], bF[4];
        #pragma unroll
        for (int m = 0; m < 4; ++m) {
          const int rA = wi * 64 + m * 16 + l15;
          aF[m] = *reinterpret_cast<const bf16x8*>(
              (char*)(&lA[cur][0]) + rA * 128 + (((kap * 4 + l4) ^ s7) << 4));
        }
        #pragma unroll
        for (int n = 0; n < 4; ++n) {
          const int rB = wj * 64 + n * 16 + l15;
          bF[n] = *reinterpret_cast<const bf16x8*>(
              (char*)(&lB[cur][0]) + rB * 128 + (((kap * 4 + l4) ^ s7) << 4));
        }
        #pragma unroll
        for (int m = 0; m < 4; ++m)
          #pragma unroll
          for (int n = 0; n < 4; ++n)
            acc[m][n] = __builtin_amdgcn_mfma_f32_16x16x32_bf16(
                aF[m], bF[n], acc[m][n], 0, 0, 0);
      }
      __builtin_amdgcn_s_setprio(0);
      // drain next-step loads (hidden under compute) + my reads done
      asm volatile("s_waitcnt vmcnt(0) lgkmcnt(0)" ::: "memory");
      __builtin_amdgcn_s_barrier();
      cur ^= 1;
    }

    // ---- tail: mask+square+pack, lane-local PV (no LDS, no barriers) ----
    // PV slot assignment: i(ks,l4,e) = (2ks+(e>>2))*16 + l4*4 + (e&3), so the
    // B-fragment is a register repack of this wave's own acc; A comes from the
    // pre-permuted Abp so each fragment is one 16B load.
    bf16x8 aP[2][4];
    #pragma unroll
    for (int ks = 0; ks < 2; ++ks)
      #pragma unroll
      for (int a = 0; a < 4; ++a)
        aP[ks][a] = *reinterpret_cast<const bf16x8*>(
            Abp + (size_t)(a * 16 + l15) * NREF + i0 + wi * 64 + ks * 32 + l4 * 8);
    int4 zr[4];
    #pragma unroll
    for (int m = 0; m < 4; ++m)
      zr[m] = *reinterpret_cast<const int4*>(Zrq + i0 + wi * 64 + m * 16 + l4 * 4);

    uint32_t lov[4][4], hiv[4][4];
    #pragma unroll
    for (int m = 0; m < 4; ++m) {
      #pragma unroll
      for (int n = 0; n < 4; ++n) {
        const int zcv = zc[n];
        const float p0 = (zr[m].x == zcv) ? pwr(acc[m][n][0], expK) : 0.f;
        const float p1 = (zr[m].y == zcv) ? pwr(acc[m][n][1], expK) : 0.f;
        const float p2 = (zr[m].z == zcv) ? pwr(acc[m][n][2], expK) : 0.f;
        const float p3 = (zr[m].w == zcv) ? pwr(acc[m][n][3], expK) : 0.f;
        lov[m][n] = (uint32_t)bfbits(p0) | ((uint32_t)bfbits(p1) << 16);
        hiv[m][n] = (uint32_t)bfbits(p2) | ((uint32_t)bfbits(p3) << 16);
      }
    }

    __builtin_amdgcn_s_setprio(1);
    #pragma unroll
    for (int ks = 0; ks < 2; ++ks) {
      #pragma unroll
      for (int n = 0; n < 4; ++n) {
        u32x4 tw;
        tw[0] = lov[2 * ks][n];
        tw[1] = hiv[2 * ks][n];
        tw[2] = lov[2 * ks + 1][n];
        tw[3] = hiv[2 * ks + 1][n];
        const bf16x8 bP = __builtin_bit_cast(bf16x8, tw);
        #pragma unroll
        for (int a = 0; a < 4; ++a)
          accO[a][n] = __builtin_amdgcn_mfma_f32_16x16x32_bf16(
              aP[ks][a], bP, accO[a][n], 0, 0, 0);
      }
    }
    __builtin_amdgcn_s_setprio(0);
  }

  // ---- cross-wi reduce (once per kernel) + write partial[split] ----
  float* rb = (float*)lA;   // 32KB: [wj][p 64][j 64] floats
  if (wi == 1) {
    #pragma unroll
    for (int a = 0; a < 4; ++a)
      #pragma unroll
      for (int n = 0; n < 4; ++n)
        #pragma unroll
        for (int r = 0; r < 4; ++r)
          rb[wj * 4096 + (a * 16 + l4 * 4 + r) * 64 + n * 16 + l15] =
              accO[a][n][r];
  }
  __syncthreads();
  if (wi == 0) {
    float* po = partial + (size_t)split * NPROPS * NIN;
    #pragma unroll
    for (int a = 0; a < 4; ++a)
      #pragma unroll
      for (int n = 0; n < 4; ++n)
        #pragma unroll
        for (int r = 0; r < 4; ++r) {
          const int p = a * 16 + l4 * 4 + r;
          const int jl = wj * 64 + n * 16 + l15;
          po[(size_t)p * NIN + j0 + jl] =
              accO[a][n][r] + rb[wj * 4096 + p * 64 + n * 16 + l15];
        }
  }
}

extern "C" void kernel_launch(void* const* d_in, const int* in_sizes, int n_in,
                              void* d_out, int out_size, void* d_ws, size_t ws_size,
                              hipStream_t stream) {
  (void)in_sizes; (void)n_in; (void)out_size;
  const float* Alpha = (const float*)d_in[0];
  const float* X_ref = (const float*)d_in[1];
  const float* desc  = (const float*)d_in[2];
  const int*   Z_ref = (const int*)d_in[3];
  const int*   Z     = (const int*)d_in[4];
  const int*   expK  = (const int*)d_in[5];
  float* out = (float*)d_out;

  char* ws = (char*)d_ws;
  size_t off = 0;
  auto alloc = [&](size_t b) { void* p = ws + off; off = (off + b + 255) & ~255ULL; return p; };

  __hip_bfloat16* Xr_bf = (__hip_bfloat16*)alloc((size_t)NREF * DFEAT * 2);
  __hip_bfloat16* Xi_bf = (__hip_bfloat16*)alloc((size_t)NIN * DFEAT * 2);
  __hip_bfloat16* Abp   = (__hip_bfloat16*)alloc((size_t)NPROPS * NREF * 2);

  // nsplit=8: grid 512 = 2/CU; per-XCD L2 working set ~2.6MB < 4MB
  int nsplit = 8;
  while (nsplit > 1 && off + (size_t)nsplit * NPROPS * NIN * 4 > ws_size) nsplit >>= 1;
  float* partial = (float*)alloc((size_t)nsplit * NPROPS * NIN * 4);

  { int n4 = NREF * DFEAT / 4;
    cvt_f32_bf16<<<dim3((n4 + 255) / 256), 256, 0, stream>>>(X_ref, Xr_bf, n4); }
  { int n4 = NIN * DFEAT / 4;
    cvt_f32_bf16<<<dim3((n4 + 255) / 256), 256, 0, stream>>>(desc, Xi_bf, n4); }
  { int n4 = NPROPS * NREF / 4;
    cvt_alpha_perm<<<dim3((n4 + 255) / 256), 256, 0, stream>>>(Alpha, Abp, n4); }

  fused_poly_kernel<<<dim3(NIN / BJ, nsplit), 256, 0, stream>>>(
      Xr_bf, Xi_bf, Abp, Z_ref, Z, expK, partial, nsplit);

  reduce_partials<<<dim3(NPROPS * NIN / 4 / 256), 256, 0, stream>>>(partial, out, nsplit);
}

// Round 5
// 83.025 us; speedup vs baseline: 2.0791x; 1.4141x over previous
//
#include <hip/hip_runtime.h>
#include <hip/hip_bf16.h>
#include <stdint.h>

// y[p, j] = sum_i Alpha[p, i] * (X_ref[i] . X_in[j])^expK * [Z_ref[i] == Z[j]]
// Grouped formulation: partition i by Z_ref and j by Z (4 element groups),
// compute 4 independent (n_z x n_z x 384) GEMM-square-GEMMs on gathered rows
// (4x fewer FLOPs than masked-dense), scatter results back through perm_j.
// Inner kernel = round-4 structure: BK=64 dbuf XOR-swizzled QK^T + lane-local PV.

typedef __attribute__((ext_vector_type(8))) short bf16x8;
typedef __attribute__((ext_vector_type(4))) float f32x4;
typedef __attribute__((ext_vector_type(4))) unsigned int u32x4;

#define DFEAT  384
#define NREF   8192
#define NIN    8192
#define NPROPS 64
#define BJ 128
#define BI 128
#define BK 64
#define KSTEPS (DFEAT / BK)        // 6
#define CAP    8704                // 8192 + 4*128 (worst-case padded slots)
#define NSTRIP (CAP / BJ)          // 68

__device__ __forceinline__ void gload_lds16(const void* g, void* l) {
  __builtin_amdgcn_global_load_lds(
      (const __attribute__((address_space(1))) void*)g,
      (__attribute__((address_space(3))) void*)l,
      16, 0, 0);
}

__device__ __forceinline__ unsigned short bfbits(float f) {
  __hip_bfloat16 h = __float2bfloat16(f);
  return __builtin_bit_cast(unsigned short, h);
}

__device__ __forceinline__ float pwr(float s, int expK) {
  if (expK == 2) return s * s;
  float r = 1.0f;
  for (int e = 0; e < expK; ++e) r *= s;
  return r;
}

// ---- stable partition of 8192 labels into 4 groups (deterministic, 1 block) ----
// perm[slot] = original index (or -1 for pad); goff[0..4] = padded group starts.
__global__ __launch_bounds__(256) void partition_kernel(
    const int* __restrict__ Zin, int* __restrict__ perm, int* __restrict__ goff) {
  __shared__ int cnt[256][4];
  __shared__ int gstart[4];
  __shared__ int gtot[4];
  const int t = threadIdx.x;
  const int base = t * 32;           // 8192 / 256

  int c[4] = {0, 0, 0, 0};
  int zloc[32];
  #pragma unroll
  for (int e = 0; e < 32; ++e) {
    zloc[e] = (Zin[base + e] - 1) & 3;   // labels are 1..4
    ++c[zloc[e]];
  }
  #pragma unroll
  for (int b = 0; b < 4; ++b) cnt[t][b] = c[b];
  __syncthreads();

  // wave w computes exclusive prefix over the 256 per-thread counts of bin w
  const int w = t >> 6, l = t & 63;
  {
    int v0 = cnt[4 * l + 0][w], v1 = cnt[4 * l + 1][w];
    int v2 = cnt[4 * l + 2][w], v3 = cnt[4 * l + 3][w];
    int s = v0 + v1 + v2 + v3;
    int inc = s;
    #pragma unroll
    for (int d = 1; d < 64; d <<= 1) {
      int o = __shfl_up(inc, d, 64);
      if (l >= d) inc += o;
    }
    const int excl = inc - s;
    cnt[4 * l + 0][w] = excl;
    cnt[4 * l + 1][w] = excl + v0;
    cnt[4 * l + 2][w] = excl + v0 + v1;
    cnt[4 * l + 3][w] = excl + v0 + v1 + v2;
    if (l == 63) gtot[w] = inc;
  }
  __syncthreads();

  if (t == 0) {
    int off = 0;
    #pragma unroll
    for (int b = 0; b < 4; ++b) {
      gstart[b] = off; goff[b] = off;
      off += ((gtot[b] + 127) >> 7) << 7;   // pad to 128
    }
    goff[4] = off;
  }
  __syncthreads();

  for (int s = t; s < CAP; s += 256) perm[s] = -1;
  __syncthreads();

  int pos[4];
  #pragma unroll
  for (int b = 0; b < 4; ++b) pos[b] = gstart[b] + cnt[t][b];
  #pragma unroll
  for (int e = 0; e < 32; ++e) {
    const int z = zloc[e];
    perm[pos[z]++] = base + e;
  }
}

// gather rows of a [8192][DFEAT] f32 array into [CAP][DFEAT] bf16 (pad -> 0)
__global__ void gather_x_bf16(const float* __restrict__ in,
                              const int* __restrict__ perm,
                              __hip_bfloat16* __restrict__ out) {
  const int idx = blockIdx.x * blockDim.x + threadIdx.x;  // CAP * DFEAT/4
  const int per_row = DFEAT / 4;
  const int slot = idx / per_row;
  const int c4 = (idx % per_row) * 4;
  const int src = perm[slot];
  ushort4 o = make_ushort4(0, 0, 0, 0);
  if (src >= 0) {
    float4 v = *reinterpret_cast<const float4*>(in + (size_t)src * DFEAT + c4);
    o.x = bfbits(v.x); o.y = bfbits(v.y); o.z = bfbits(v.z); o.w = bfbits(v.w);
  }
  *reinterpret_cast<ushort4*>(out + (size_t)slot * DFEAT + c4) = o;
}

// Alpha -> gathered bf16 [NPROPS][CAP], permuted within each 32-slot block so
// the PV A-fragment is one 16B load:
//   out[p][32b + l4*8 + eh*4 + r] = Alpha[p][perm_i[32b + eh*16 + l4*4 + r]]
__global__ void gather_alpha_perm(const float* __restrict__ in,
                                  const int* __restrict__ perm,
                                  __hip_bfloat16* __restrict__ out) {
  const int t = blockIdx.x * blockDim.x + threadIdx.x;    // NPROPS * CAP/4
  const int per_row = CAP / 4;
  const int p  = t / per_row;
  const int c4 = t % per_row;
  const int b   = c4 >> 3;
  const int g   = c4 & 7;
  const int l4g = g >> 1;
  const int eh  = g & 1;
  ushort4 o;
  unsigned short* op = &o.x;
  #pragma unroll
  for (int r = 0; r < 4; ++r) {
    const int slot = b * 32 + eh * 16 + l4g * 4 + r;
    const int src = perm[slot];
    op[r] = (src >= 0) ? bfbits(in[(size_t)p * NREF + src]) : (unsigned short)0;
  }
  *reinterpret_cast<ushort4*>(out + (size_t)p * CAP + b * 32 + l4g * 8 + eh * 4) = o;
}

// sum nsplit partials and scatter slot -> original column via perm_j
__global__ void reduce_scatter(const float* __restrict__ partial,
                               const int* __restrict__ permj,
                               float* __restrict__ out, int nsplit) {
  const int idx = blockIdx.x * blockDim.x + threadIdx.x;  // NPROPS * CAP
  const int p = idx / CAP;
  const int slot = idx % CAP;
  const int dst = permj[slot];
  if (dst < 0) return;
  float s = 0.f;
  for (int sp = 0; sp < nsplit; ++sp)
    s += partial[(size_t)sp * NPROPS * CAP + (size_t)p * CAP + slot];
  out[(size_t)p * NIN + dst] = s;
}

__global__ __launch_bounds__(256, 2) void fused_poly_kernel(
    const __hip_bfloat16* __restrict__ Xr,   // [CAP][DFEAT] gathered ref rows
    const __hip_bfloat16* __restrict__ Xi,   // [CAP][DFEAT] gathered query rows
    const __hip_bfloat16* __restrict__ Abp,  // [NPROPS][CAP] gathered+permuted
    const int* __restrict__ ioff,            // [5] padded i-group offsets
    const int* __restrict__ joff,            // [5] padded j-group offsets
    const int* __restrict__ expKp,
    float* __restrict__ partial,             // [nsplit][NPROPS][CAP]
    int nsplit)
{
  const int j0 = blockIdx.x * BJ;            // slot space
  const int split = blockIdx.y;

  // group of this j-strip (beyond-end strips fall into group 3: all-zero B)
  int grp = 0;
  grp += (j0 >= joff[1]);
  grp += (j0 >= joff[2]);
  grp += (j0 >= joff[3]);
  const int ibase = ioff[grp];
  const int ntiles_g = (ioff[grp + 1] - ibase) / BI;

  const int tb = ntiles_g / nsplit;
  const int rem = ntiles_g % nsplit;
  const int ntiles = tb + (split < rem ? 1 : 0);
  const int tile_begin = split * tb + (split < rem ? split : rem);

  const int tid  = threadIdx.x;
  const int wid  = tid >> 6;
  const int lane = tid & 63;
  const int l15  = lane & 15;
  const int l4   = lane >> 4;
  const int s7   = l15 & 7;
  const int wi   = wid >> 1;
  const int wj   = wid & 1;

  __shared__ alignas(16) __hip_bfloat16 lA[2][BI * BK];
  __shared__ alignas(16) __hip_bfloat16 lB[2][BJ * BK];

  const int expK = *expKp;

  const int srow = lane >> 3;
  const int scol = ((lane & 7) ^ srow) * 8;

  auto stage = [&](int buf, int i0s, int kks) {
    #pragma unroll
    for (int q = 0; q < 4; ++q) {
      const int c = wid * 4 + q;
      const int grow = c * 8 + srow;
      const size_t gc = (size_t)kks * BK + scol;
      gload_lds16(Xr + (size_t)(i0s + grow) * DFEAT + gc, &lA[buf][c * 512]);
      gload_lds16(Xi + (size_t)(j0  + grow) * DFEAT + gc, &lB[buf][c * 512]);
    }
  };

  f32x4 accO[4][4];
  #pragma unroll
  for (int a = 0; a < 4; ++a)
    #pragma unroll
    for (int n = 0; n < 4; ++n)
      accO[a][n] = (f32x4){0.f, 0.f, 0.f, 0.f};

  if (ntiles > 0) {
    int cur = 0;
    stage(0, ibase + tile_begin * BI, 0);
    asm volatile("s_waitcnt vmcnt(0)" ::: "memory");
    __builtin_amdgcn_s_barrier();

    for (int t = 0; t < ntiles; ++t) {
      const int i0 = ibase + (tile_begin + t) * BI;

      f32x4 acc[4][4];
      #pragma unroll
      for (int m = 0; m < 4; ++m)
        #pragma unroll
        for (int n = 0; n < 4; ++n)
          acc[m][n] = (f32x4){0.f, 0.f, 0.f, 0.f};

      for (int kk = 0; kk < KSTEPS; ++kk) {
        if (kk < KSTEPS - 1) {
          stage(cur ^ 1, i0, kk + 1);
        } else if (t < ntiles - 1) {
          stage(cur ^ 1, i0 + BI, 0);
        }

        __builtin_amdgcn_s_setprio(1);
        #pragma unroll
        for (int kap = 0; kap < 2; ++kap) {
          bf16x8 aF[4], bF[4];
          #pragma unroll
          for (int m = 0; m < 4; ++m) {
            const int rA = wi * 64 + m * 16 + l15;
            aF[m] = *reinterpret_cast<const bf16x8*>(
                (char*)(&lA[cur][0]) + rA * 128 + (((kap * 4 + l4) ^ s7) << 4));
          }
          #pragma unroll
          for (int n = 0; n < 4; ++n) {
            const int rB = wj * 64 + n * 16 + l15;
            bF[n] = *reinterpret_cast<const bf16x8*>(
                (char*)(&lB[cur][0]) + rB * 128 + (((kap * 4 + l4) ^ s7) << 4));
          }
          #pragma unroll
          for (int m = 0; m < 4; ++m)
            #pragma unroll
            for (int n = 0; n < 4; ++n)
              acc[m][n] = __builtin_amdgcn_mfma_f32_16x16x32_bf16(
                  aF[m], bF[n], acc[m][n], 0, 0, 0);
        }
        __builtin_amdgcn_s_setprio(0);
        asm volatile("s_waitcnt vmcnt(0) lgkmcnt(0)" ::: "memory");
        __builtin_amdgcn_s_barrier();
        cur ^= 1;
      }

      // ---- tail: square+pack (no mask needed — groups pre-matched), PV ----
      bf16x8 aP[2][4];
      #pragma unroll
      for (int ks = 0; ks < 2; ++ks)
        #pragma unroll
        for (int a = 0; a < 4; ++a)
          aP[ks][a] = *reinterpret_cast<const bf16x8*>(
              Abp + (size_t)(a * 16 + l15) * CAP + i0 + wi * 64 + ks * 32 + l4 * 8);

      uint32_t lov[4][4], hiv[4][4];
      #pragma unroll
      for (int m = 0; m < 4; ++m) {
        #pragma unroll
        for (int n = 0; n < 4; ++n) {
          const float p0 = pwr(acc[m][n][0], expK);
          const float p1 = pwr(acc[m][n][1], expK);
          const float p2 = pwr(acc[m][n][2], expK);
          const float p3 = pwr(acc[m][n][3], expK);
          lov[m][n] = (uint32_t)bfbits(p0) | ((uint32_t)bfbits(p1) << 16);
          hiv[m][n] = (uint32_t)bfbits(p2) | ((uint32_t)bfbits(p3) << 16);
        }
      }

      __builtin_amdgcn_s_setprio(1);
      #pragma unroll
      for (int ks = 0; ks < 2; ++ks) {
        #pragma unroll
        for (int n = 0; n < 4; ++n) {
          u32x4 tw;
          tw[0] = lov[2 * ks][n];
          tw[1] = hiv[2 * ks][n];
          tw[2] = lov[2 * ks + 1][n];
          tw[3] = hiv[2 * ks + 1][n];
          const bf16x8 bP = __builtin_bit_cast(bf16x8, tw);
          #pragma unroll
          for (int a = 0; a < 4; ++a)
            accO[a][n] = __builtin_amdgcn_mfma_f32_16x16x32_bf16(
                aP[ks][a], bP, accO[a][n], 0, 0, 0);
        }
      }
      __builtin_amdgcn_s_setprio(0);
    }
  }

  // ---- cross-wi reduce + write partial[split] ----
  float* rb = (float*)lA;   // 32KB scratch: [wj][p 64][j 64]
  if (wi == 1) {
    #pragma unroll
    for (int a = 0; a < 4; ++a)
      #pragma unroll
      for (int n = 0; n < 4; ++n)
        #pragma unroll
        for (int r = 0; r < 4; ++r)
          rb[wj * 4096 + (a * 16 + l4 * 4 + r) * 64 + n * 16 + l15] =
              accO[a][n][r];
  }
  __syncthreads();
  if (wi == 0) {
    float* po = partial + (size_t)split * NPROPS * CAP;
    #pragma unroll
    for (int a = 0; a < 4; ++a)
      #pragma unroll
      for (int n = 0; n < 4; ++n)
        #pragma unroll
        for (int r = 0; r < 4; ++r) {
          const int p = a * 16 + l4 * 4 + r;
          const int jl = wj * 64 + n * 16 + l15;
          po[(size_t)p * CAP + j0 + jl] =
              accO[a][n][r] + rb[wj * 4096 + p * 64 + n * 16 + l15];
        }
  }
}

extern "C" void kernel_launch(void* const* d_in, const int* in_sizes, int n_in,
                              void* d_out, int out_size, void* d_ws, size_t ws_size,
                              hipStream_t stream) {
  (void)in_sizes; (void)n_in; (void)out_size;
  const float* Alpha = (const float*)d_in[0];
  const float* X_ref = (const float*)d_in[1];
  const float* desc  = (const float*)d_in[2];
  const int*   Z_ref = (const int*)d_in[3];
  const int*   Z     = (const int*)d_in[4];
  const int*   expK  = (const int*)d_in[5];
  float* out = (float*)d_out;

  char* ws = (char*)d_ws;
  size_t off = 0;
  auto alloc = [&](size_t b) { void* p = ws + off; off = (off + b + 255) & ~255ULL; return p; };

  int* perm_i = (int*)alloc(CAP * 4);
  int* perm_j = (int*)alloc(CAP * 4);
  int* ioff   = (int*)alloc(8 * 4);
  int* joff   = (int*)alloc(8 * 4);
  __hip_bfloat16* Xr_g = (__hip_bfloat16*)alloc((size_t)CAP * DFEAT * 2);
  __hip_bfloat16* Xi_g = (__hip_bfloat16*)alloc((size_t)CAP * DFEAT * 2);
  __hip_bfloat16* Ab_g = (__hip_bfloat16*)alloc((size_t)NPROPS * CAP * 2);

  int nsplit = 8;
  while (nsplit > 1 && off + (size_t)nsplit * NPROPS * CAP * 4 > ws_size) nsplit >>= 1;
  float* partial = (float*)alloc((size_t)nsplit * NPROPS * CAP * 4);

  partition_kernel<<<1, 256, 0, stream>>>(Z_ref, perm_i, ioff);
  partition_kernel<<<1, 256, 0, stream>>>(Z,     perm_j, joff);

  { int nt = CAP * (DFEAT / 4);
    gather_x_bf16<<<dim3(nt / 256), 256, 0, stream>>>(X_ref, perm_i, Xr_g); }
  { int nt = CAP * (DFEAT / 4);
    gather_x_bf16<<<dim3(nt / 256), 256, 0, stream>>>(desc, perm_j, Xi_g); }
  { int nt = NPROPS * (CAP / 4);
    gather_alpha_perm<<<dim3(nt / 256), 256, 0, stream>>>(Alpha, perm_i, Ab_g); }

  fused_poly_kernel<<<dim3(NSTRIP, nsplit), 256, 0, stream>>>(
      Xr_g, Xi_g, Ab_g, ioff, joff, expK, partial, nsplit);

  reduce_scatter<<<dim3(NPROPS * CAP / 256), 256, 0, stream>>>(
      partial, perm_j, out, nsplit);
}

// Round 6
// 77.667 us; speedup vs baseline: 2.2225x; 1.0690x over previous
//
#include <hip/hip_runtime.h>
#include <hip/hip_bf16.h>
#include <stdint.h>

// y[p, j] = sum_i Alpha[p, i] * (X_ref[i] . X_in[j])^expK * [Z_ref[i] == Z[j]]
// Grouped formulation (4 element groups), fused QK^T -> square -> lane-local PV.
// Round-6: T4 counted-vmcnt pipeline (never drain to 0 in the K-loop),
// XCD-chunked bijective block swizzle for per-XCD L2 residency, pad-strip
// early exit, and launch fusion (4 kernels total).

typedef __attribute__((ext_vector_type(8))) short bf16x8;
typedef __attribute__((ext_vector_type(4))) float f32x4;
typedef __attribute__((ext_vector_type(4))) unsigned int u32x4;

#define DFEAT  384
#define NREF   8192
#define NIN    8192
#define NPROPS 64
#define BJ 128
#define BI 128
#define BK 64
#define KSTEPS (DFEAT / BK)        // 6
#define CAP    8704                // 8192 + 4*128 (worst-case padded slots)
#define NSTRIP (CAP / BJ)          // 68

__device__ __forceinline__ void gload_lds16(const void* g, void* l) {
  __builtin_amdgcn_global_load_lds(
      (const __attribute__((address_space(1))) void*)g,
      (__attribute__((address_space(3))) void*)l,
      16, 0, 0);
}

__device__ __forceinline__ unsigned short bfbits(float f) {
  __hip_bfloat16 h = __float2bfloat16(f);
  return __builtin_bit_cast(unsigned short, h);
}

__device__ __forceinline__ float pwr(float s, int expK) {
  if (expK == 2) return s * s;
  float r = 1.0f;
  for (int e = 0; e < expK; ++e) r *= s;
  return r;
}

// ---- stable partition of both label arrays (2 blocks, one each) ----
__global__ __launch_bounds__(256) void partition2_kernel(
    const int* __restrict__ Za, const int* __restrict__ Zb,
    int* __restrict__ perma, int* __restrict__ permb,
    int* __restrict__ goffa, int* __restrict__ goffb) {
  const int* Zin = blockIdx.x ? Zb : Za;
  int* perm = blockIdx.x ? permb : perma;
  int* goff = blockIdx.x ? goffb : goffa;

  __shared__ int cnt[256][4];
  __shared__ int gstart[4];
  __shared__ int gtot[4];
  const int t = threadIdx.x;
  const int base = t * 32;           // 8192 / 256

  int c[4] = {0, 0, 0, 0};
  int zloc[32];
  #pragma unroll
  for (int e = 0; e < 32; ++e) {
    zloc[e] = (Zin[base + e] - 1) & 3;   // labels are 1..4
    ++c[zloc[e]];
  }
  #pragma unroll
  for (int b = 0; b < 4; ++b) cnt[t][b] = c[b];
  __syncthreads();

  const int w = t >> 6, l = t & 63;
  {
    int v0 = cnt[4 * l + 0][w], v1 = cnt[4 * l + 1][w];
    int v2 = cnt[4 * l + 2][w], v3 = cnt[4 * l + 3][w];
    int s = v0 + v1 + v2 + v3;
    int inc = s;
    #pragma unroll
    for (int d = 1; d < 64; d <<= 1) {
      int o = __shfl_up(inc, d, 64);
      if (l >= d) inc += o;
    }
    const int excl = inc - s;
    cnt[4 * l + 0][w] = excl;
    cnt[4 * l + 1][w] = excl + v0;
    cnt[4 * l + 2][w] = excl + v0 + v1;
    cnt[4 * l + 3][w] = excl + v0 + v1 + v2;
    if (l == 63) gtot[w] = inc;
  }
  __syncthreads();

  if (t == 0) {
    int off = 0;
    #pragma unroll
    for (int b = 0; b < 4; ++b) {
      gstart[b] = off; goff[b] = off;
      off += ((gtot[b] + 127) >> 7) << 7;   // pad to 128
    }
    goff[4] = off;
  }
  __syncthreads();

  for (int s = t; s < CAP; s += 256) perm[s] = -1;
  __syncthreads();

  int pos[4];
  #pragma unroll
  for (int b = 0; b < 4; ++b) pos[b] = gstart[b] + cnt[t][b];
  #pragma unroll
  for (int e = 0; e < 32; ++e) {
    const int z = zloc[e];
    perm[pos[z]++] = base + e;
  }
}

// ---- merged gather: Xr (perm_i), Xi (perm_j), Alpha (perm_i, permuted) ----
#define XSEC (CAP * (DFEAT / 4) / 256)     // 3264 blocks per X section
__global__ void gather_all(const float* __restrict__ Xr_in,
                           const float* __restrict__ Xi_in,
                           const float* __restrict__ Al_in,
                           const int* __restrict__ perm_i,
                           const int* __restrict__ perm_j,
                           __hip_bfloat16* __restrict__ Xr_g,
                           __hip_bfloat16* __restrict__ Xi_g,
                           __hip_bfloat16* __restrict__ Ab_g) {
  const int b = blockIdx.x;
  if (b < 2 * XSEC) {
    const bool isA = (b < XSEC);
    const float* in = isA ? Xr_in : Xi_in;
    const int* perm = isA ? perm_i : perm_j;
    __hip_bfloat16* out = isA ? Xr_g : Xi_g;
    const int idx = (isA ? b : b - XSEC) * 256 + threadIdx.x;
    const int per_row = DFEAT / 4;
    const int slot = idx / per_row;
    const int c4 = (idx % per_row) * 4;
    const int src = perm[slot];
    ushort4 o = make_ushort4(0, 0, 0, 0);
    if (src >= 0) {
      float4 v = *reinterpret_cast<const float4*>(in + (size_t)src * DFEAT + c4);
      o.x = bfbits(v.x); o.y = bfbits(v.y); o.z = bfbits(v.z); o.w = bfbits(v.w);
    }
    *reinterpret_cast<ushort4*>(out + (size_t)slot * DFEAT + c4) = o;
  } else {
    // Ab_g[p][32b + l4*8 + eh*4 + r] = Alpha[p][perm_i[32b + eh*16 + l4*4 + r]]
    const int t = (b - 2 * XSEC) * 256 + threadIdx.x;   // NPROPS * CAP/4
    const int per_row = CAP / 4;
    const int p  = t / per_row;
    const int c4 = t % per_row;
    const int blk = c4 >> 3;
    const int g   = c4 & 7;
    const int l4g = g >> 1;
    const int eh  = g & 1;
    ushort4 o;
    unsigned short* op = &o.x;
    #pragma unroll
    for (int r = 0; r < 4; ++r) {
      const int slot = blk * 32 + eh * 16 + l4g * 4 + r;
      const int src = perm_i[slot];
      op[r] = (src >= 0) ? bfbits(Al_in[(size_t)p * NREF + src]) : (unsigned short)0;
    }
    *reinterpret_cast<ushort4*>(Ab_g + (size_t)p * CAP + blk * 32 + l4g * 8 + eh * 4) = o;
  }
}

// sum nsplit partials and scatter slot -> original column via perm_j
__global__ void reduce_scatter(const float* __restrict__ partial,
                               const int* __restrict__ permj,
                               float* __restrict__ out, int nsplit) {
  const int idx = blockIdx.x * blockDim.x + threadIdx.x;  // NPROPS * CAP
  const int p = idx / CAP;
  const int slot = idx % CAP;
  const int dst = permj[slot];
  if (dst < 0) return;
  float s = 0.f;
  for (int sp = 0; sp < nsplit; ++sp)
    s += partial[(size_t)sp * NPROPS * CAP + (size_t)p * CAP + slot];
  out[(size_t)p * NIN + dst] = s;
}

__global__ __launch_bounds__(256, 2) void fused_poly_kernel(
    const __hip_bfloat16* __restrict__ Xr,   // [CAP][DFEAT] gathered ref rows
    const __hip_bfloat16* __restrict__ Xi,   // [CAP][DFEAT] gathered query rows
    const __hip_bfloat16* __restrict__ Abp,  // [NPROPS][CAP] gathered+permuted
    const int* __restrict__ ioff,            // [5] padded i-group offsets
    const int* __restrict__ joff,            // [5] padded j-group offsets
    const int* __restrict__ expKp,
    float* __restrict__ partial,             // [nsplit][NPROPS][CAP]
    int nsplit, int chunk)                   // chunk = gridDim.x / 8
{
  // XCD-chunked bijective swizzle: consecutive newflat (one XCD) = consecutive
  // (strip-major) blocks -> each XCD works one group's strips, all splits.
  const int flat = blockIdx.x;
  const int newflat = (flat & 7) * chunk + (flat >> 3);
  const int strip = newflat / nsplit;
  const int split = newflat % nsplit;
  const int j0 = strip * BJ;

  if (j0 >= joff[4]) return;                 // fully-pad strip: nothing to do

  int grp = 0;
  grp += (j0 >= joff[1]);
  grp += (j0 >= joff[2]);
  grp += (j0 >= joff[3]);
  const int ibase = ioff[grp];
  const int ntiles_g = (ioff[grp + 1] - ibase) / BI;

  const int tb = ntiles_g / nsplit;
  const int rem = ntiles_g % nsplit;
  const int ntiles = tb + (split < rem ? 1 : 0);
  const int tile_begin = split * tb + (split < rem ? split : rem);

  const int tid  = threadIdx.x;
  const int wid  = tid >> 6;
  const int lane = tid & 63;
  const int l15  = lane & 15;
  const int l4   = lane >> 4;
  const int s7   = l15 & 7;
  const int wi   = wid >> 1;
  const int wj   = wid & 1;

  __shared__ alignas(16) __hip_bfloat16 lA[2][BI * BK];
  __shared__ alignas(16) __hip_bfloat16 lB[2][BJ * BK];

  const int expK = *expKp;

  const int srow = lane >> 3;
  const int scol = ((lane & 7) ^ srow) * 8;

  auto stage = [&](int buf, int i0s, int kks) {
    #pragma unroll
    for (int q = 0; q < 4; ++q) {
      const int c = wid * 4 + q;
      const int grow = c * 8 + srow;
      const size_t gc = (size_t)kks * BK + scol;
      gload_lds16(Xr + (size_t)(i0s + grow) * DFEAT + gc, &lA[buf][c * 512]);
      gload_lds16(Xi + (size_t)(j0  + grow) * DFEAT + gc, &lB[buf][c * 512]);
    }
  };

  f32x4 accO[4][4];
  #pragma unroll
  for (int a = 0; a < 4; ++a)
    #pragma unroll
    for (int n = 0; n < 4; ++n)
      accO[a][n] = (f32x4){0.f, 0.f, 0.f, 0.f};

  if (ntiles > 0) {
    int cur = 0;
    stage(0, ibase + tile_begin * BI, 0);    // 8 loads in flight; no drain here

    for (int t = 0; t < ntiles; ++t) {
      const int i0 = ibase + (tile_begin + t) * BI;

      f32x4 acc[4][4];
      #pragma unroll
      for (int m = 0; m < 4; ++m)
        #pragma unroll
        for (int n = 0; n < 4; ++n)
          acc[m][n] = (f32x4){0.f, 0.f, 0.f, 0.f};

      for (int kk = 0; kk < KSTEPS; ++kk) {
        // issue next prefetch (T4: keep it in flight across the compute phase)
        bool staged = true;
        if (kk < KSTEPS - 1) {
          stage(cur ^ 1, i0, kk + 1);
        } else if (t < ntiles - 1) {
          stage(cur ^ 1, i0 + BI, 0);
        } else {
          staged = false;
        }
        // wait only for the PREVIOUS stage (the buffer we're about to read)
        if (staged) asm volatile("s_waitcnt vmcnt(8)" ::: "memory");
        else        asm volatile("s_waitcnt vmcnt(0)" ::: "memory");
        __builtin_amdgcn_s_barrier();        // all waves' cur-loads landed

        __builtin_amdgcn_s_setprio(1);
        #pragma unroll
        for (int kap = 0; kap < 2; ++kap) {
          bf16x8 aF[4], bF[4];
          #pragma unroll
          for (int m = 0; m < 4; ++m) {
            const int rA = wi * 64 + m * 16 + l15;
            aF[m] = *reinterpret_cast<const bf16x8*>(
                (char*)(&lA[cur][0]) + rA * 128 + (((kap * 4 + l4) ^ s7) << 4));
          }
          #pragma unroll
          for (int n = 0; n < 4; ++n) {
            const int rB = wj * 64 + n * 16 + l15;
            bF[n] = *reinterpret_cast<const bf16x8*>(
                (char*)(&lB[cur][0]) + rB * 128 + (((kap * 4 + l4) ^ s7) << 4));
          }
          #pragma unroll
          for (int m = 0; m < 4; ++m)
            #pragma unroll
            for (int n = 0; n < 4; ++n)
              acc[m][n] = __builtin_amdgcn_mfma_f32_16x16x32_bf16(
                  aF[m], bF[n], acc[m][n], 0, 0, 0);
        }
        __builtin_amdgcn_s_setprio(0);
        asm volatile("s_waitcnt lgkmcnt(0)" ::: "memory");  // my reads done
        __builtin_amdgcn_s_barrier();        // nobody still reading cur
        cur ^= 1;
      }

      // ---- tail: square+pack (groups pre-matched, no mask), lane-local PV ----
      bf16x8 aP[2][4];
      #pragma unroll
      for (int ks = 0; ks < 2; ++ks)
        #pragma unroll
        for (int a = 0; a < 4; ++a)
          aP[ks][a] = *reinterpret_cast<const bf16x8*>(
              Abp + (size_t)(a * 16 + l15) * CAP + i0 + wi * 64 + ks * 32 + l4 * 8);

      uint32_t lov[4][4], hiv[4][4];
      #pragma unroll
      for (int m = 0; m < 4; ++m) {
        #pragma unroll
        for (int n = 0; n < 4; ++n) {
          const float p0 = pwr(acc[m][n][0], expK);
          const float p1 = pwr(acc[m][n][1], expK);
          const float p2 = pwr(acc[m][n][2], expK);
          const float p3 = pwr(acc[m][n][3], expK);
          lov[m][n] = (uint32_t)bfbits(p0) | ((uint32_t)bfbits(p1) << 16);
          hiv[m][n] = (uint32_t)bfbits(p2) | ((uint32_t)bfbits(p3) << 16);
        }
      }

      __builtin_amdgcn_s_setprio(1);
      #pragma unroll
      for (int ks = 0; ks < 2; ++ks) {
        #pragma unroll
        for (int n = 0; n < 4; ++n) {
          u32x4 tw;
          tw[0] = lov[2 * ks][n];
          tw[1] = hiv[2 * ks][n];
          tw[2] = lov[2 * ks + 1][n];
          tw[3] = hiv[2 * ks + 1][n];
          const bf16x8 bP = __builtin_bit_cast(bf16x8, tw);
          #pragma unroll
          for (int a = 0; a < 4; ++a)
            accO[a][n] = __builtin_amdgcn_mfma_f32_16x16x32_bf16(
                aP[ks][a], bP, accO[a][n], 0, 0, 0);
        }
      }
      __builtin_amdgcn_s_setprio(0);
    }
  }

  // ---- cross-wi reduce + write partial[split] ----
  float* rb = (float*)lA;   // 32KB scratch: [wj][p 64][j 64]
  if (wi == 1) {
    #pragma unroll
    for (int a = 0; a < 4; ++a)
      #pragma unroll
      for (int n = 0; n < 4; ++n)
        #pragma unroll
        for (int r = 0; r < 4; ++r)
          rb[wj * 4096 + (a * 16 + l4 * 4 + r) * 64 + n * 16 + l15] =
              accO[a][n][r];
  }
  __syncthreads();
  if (wi == 0) {
    float* po = partial + (size_t)split * NPROPS * CAP;
    #pragma unroll
    for (int a = 0; a < 4; ++a)
      #pragma unroll
      for (int n = 0; n < 4; ++n)
        #pragma unroll
        for (int r = 0; r < 4; ++r) {
          const int p = a * 16 + l4 * 4 + r;
          const int jl = wj * 64 + n * 16 + l15;
          po[(size_t)p * CAP + j0 + jl] =
              accO[a][n][r] + rb[wj * 4096 + p * 64 + n * 16 + l15];
        }
  }
}

extern "C" void kernel_launch(void* const* d_in, const int* in_sizes, int n_in,
                              void* d_out, int out_size, void* d_ws, size_t ws_size,
                              hipStream_t stream) {
  (void)in_sizes; (void)n_in; (void)out_size;
  const float* Alpha = (const float*)d_in[0];
  const float* X_ref = (const float*)d_in[1];
  const float* desc  = (const float*)d_in[2];
  const int*   Z_ref = (const int*)d_in[3];
  const int*   Z     = (const int*)d_in[4];
  const int*   expK  = (const int*)d_in[5];
  float* out = (float*)d_out;

  char* ws = (char*)d_ws;
  size_t off = 0;
  auto alloc = [&](size_t b) { void* p = ws + off; off = (off + b + 255) & ~255ULL; return p; };

  int* perm_i = (int*)alloc(CAP * 4);
  int* perm_j = (int*)alloc(CAP * 4);
  int* ioff   = (int*)alloc(8 * 4);
  int* joff   = (int*)alloc(8 * 4);
  __hip_bfloat16* Xr_g = (__hip_bfloat16*)alloc((size_t)CAP * DFEAT * 2);
  __hip_bfloat16* Xi_g = (__hip_bfloat16*)alloc((size_t)CAP * DFEAT * 2);
  __hip_bfloat16* Ab_g = (__hip_bfloat16*)alloc((size_t)NPROPS * CAP * 2);

  int nsplit = 8;
  while (nsplit > 1 && off + (size_t)nsplit * NPROPS * CAP * 4 > ws_size) nsplit >>= 1;
  float* partial = (float*)alloc((size_t)nsplit * NPROPS * CAP * 4);

  partition2_kernel<<<dim3(2), 256, 0, stream>>>(
      Z_ref, Z, perm_i, perm_j, ioff, joff);

  gather_all<<<dim3(2 * XSEC + NPROPS * (CAP / 4) / 256), 256, 0, stream>>>(
      X_ref, desc, Alpha, perm_i, perm_j, Xr_g, Xi_g, Ab_g);

  const int grid = NSTRIP * nsplit;          // 544 at nsplit=8 (multiple of 8)
  fused_poly_kernel<<<dim3(grid), 256, 0, stream>>>(
      Xr_g, Xi_g, Ab_g, ioff, joff, expK, partial, nsplit, grid / 8);

  reduce_scatter<<<dim3(NPROPS * CAP / 256), 256, 0, stream>>>(
      partial, perm_j, out, nsplit);
}